// Round 4
// baseline (800.139 us; speedup 1.0000x reference)
//
#include <hip/hip_runtime.h>
#include <hip/hip_bf16.h>

// PointProp for MI355X (gfx950) — R8.
//   kP: prep (Wc fold, bias chain, ZERO sync flags)   kC: pack weights (bf16)
//   kMain (512 blocks, co-resident producer/consumer pipeline):
//     blocks 0..255   PRODUCER c: stream comp rows [c*256,+256) in 4 sub-chunks
//                     of 64 rows (k-serial, R4-kA order), write bf16 csum,
//                     __threadfence + device-scope release flag per sub-chunk.
//     blocks 256..511 CONSUMER c: per sub-chunk, acquire-spin on flag, then
//                     run the verified R7 MLP (register weight dbuf, no
//                     barriers, wave-private 8KB act tile) on its 16 rows.
//   Producers never wait -> deadlock-free. All 512 blocks co-resident
//   (8 waves/CU, <=32KB LDS, <=256 VGPR). The csum-dependent MLP now overlaps
//   the 537MB comp stream instead of running after it.
// Math: out = L4(relu(L3(relu(L2(relu(sig@W0s^T + csum@Wc^T + bias1))))))
// with Wc = W0r@Wu@Wm folded (linearity), H padded 132->160.

typedef float  f32x4  __attribute__((ext_vector_type(4)));
typedef __bf16 bf16x8 __attribute__((ext_vector_type(8)));
typedef unsigned int   u32x2 __attribute__((ext_vector_type(2)));
typedef unsigned short u16x8 __attribute__((ext_vector_type(8)));

__device__ __forceinline__ unsigned short f2bf(float f) {
  unsigned int u = __builtin_bit_cast(unsigned int, f);
  u += 0x7fffu + ((u >> 16) & 1u);   // RNE
  return (unsigned short)(u >> 16);
}

__device__ __forceinline__ u32x2 pack4(f32x4 v) {
  u32x2 r;
  r[0] = (unsigned)f2bf(v[0]) | ((unsigned)f2bf(v[1]) << 16);
  r[1] = (unsigned)f2bf(v[2]) | ((unsigned)f2bf(v[3]) << 16);
  return r;
}

// ---------------- Kernel P: all prep (Wc, bias1, padded biases, flags) ------
__global__ __launch_bounds__(256) void kP(
    const float* __restrict__ W0, const float* __restrict__ Wu,
    const float* __restrict__ Wm, const float* __restrict__ bm,
    const float* __restrict__ bu, const float* __restrict__ b0,
    const float* __restrict__ b1, const float* __restrict__ b2,
    float* __restrict__ Wc, float* __restrict__ bias1,
    float* __restrict__ b1p, float* __restrict__ b2p,
    int* __restrict__ flags) {
  const int b = blockIdx.x;
  const int d = threadIdx.x;
  if (b < 132) {
    __shared__ float u[256];
    const int h = b;
    float s = 0.f;
#pragma unroll 8
    for (int i = 0; i < 256; ++i) s += W0[h * 512 + 256 + i] * Wu[i * 256 + d];
    u[d] = s;
    __syncthreads();
    float s2 = 0.f;
#pragma unroll 8
    for (int j = 0; j < 256; ++j) s2 += u[j] * Wm[j * 256 + d];
    Wc[h * 256 + d] = s2;
  } else {
    // zero the 1024 producer->consumer flags (ws may be poisoned)
    flags[d] = 0; flags[d + 256] = 0; flags[d + 512] = 0; flags[d + 768] = 0;
    __shared__ float bml[256];
    __shared__ float rbl[256];
    bml[d] = bm[d];
    __syncthreads();
    {
      const f32x4* wr = (const f32x4*)(Wu + d * 256);
      const f32x4* bm4 = (const f32x4*)bml;
      float s = 0.f;
#pragma unroll 8
      for (int i = 0; i < 64; ++i) {
        f32x4 w = wr[i], v = bm4[i];
        s += w[0] * v[0] + w[1] * v[1] + w[2] * v[2] + w[3] * v[3];
      }
      rbl[d] = 8.f * s + bu[d];
    }
    __syncthreads();
    if (d < 160) {
      float v = 0.f;
      if (d < 132) {
        float s = 0.f;
#pragma unroll 8
        for (int j = 0; j < 256; ++j) s += W0[d * 512 + 256 + j] * rbl[j];
        v = b0[d] + s;
      }
      bias1[d] = v;
      b1p[d] = (d < 132) ? b1[d] : 0.f;
      b2p[d] = (d < 132) ? b2[d] : 0.f;
    }
  }
}

// ---------------- Kernel C: pack weights to MFMA B-frag order (bf16) --------
// Chunk (kk,nt) = 1024B: lane l holds B[kk*32+(l>>4)*8+j][nt*16+(l&15)], j=0..7.
// L1: K=512,N=160; L2/L3: 160x160; L4: 160x256. P1..P4 CONTIGUOUS in ws
// (uniform chunk offset: chunk c at c*10240 for c=0..25; L4 halves at
//  266240 + h*8192).
__global__ __launch_bounds__(256) void kC(
    const float* __restrict__ W0, const float* __restrict__ Wc,
    const float* __restrict__ W1, const float* __restrict__ W2,
    const float* __restrict__ W3,
    unsigned short* __restrict__ P1, unsigned short* __restrict__ P2,
    unsigned short* __restrict__ P3, unsigned short* __restrict__ P4) {
  int e = blockIdx.x * 256 + threadIdx.x;
  if (e >= 174080) return;
  unsigned short* dst; int NT, rel, mode;
  if (e < 81920)       { dst = P1; NT = 10; rel = e;          mode = 0; }
  else if (e < 107520) { dst = P2; NT = 10; rel = e - 81920;  mode = 1; }
  else if (e < 133120) { dst = P3; NT = 10; rel = e - 107520; mode = 2; }
  else                 { dst = P4; NT = 16; rel = e - 133120; mode = 3; }
  int chunk = rel >> 9, q = rel & 511;
  int lane = q >> 3, j = q & 7;
  int kk = chunk / NT, nt = chunk - kk * NT;
  int k = kk * 32 + (lane >> 4) * 8 + j;
  int n = nt * 16 + (lane & 15);
  float v = 0.f;
  if (mode == 0) {
    if (n < 132) v = (k < 256) ? W0[n * 512 + k] : Wc[n * 256 + (k - 256)];
  } else if (mode == 1) {
    if (n < 132 && k < 132) v = W1[n * 132 + k];
  } else if (mode == 2) {
    if (n < 132 && k < 132) v = W2[n * 132 + k];
  } else {
    if (k < 132) v = W3[n * 132 + k];
  }
  dst[rel] = f2bf(v);
}

// ---- per-wave weight issue (direct L2 -> VGPR, coalesced 1KB per frag) ----
#define WISS(BUF, CHUNK)                                                     \
  {                                                                          \
    _Pragma("unroll") for (int nt = 0; nt < 10; ++nt)                        \
        BUF[nt] = *(const bf16x8*)(Pb + (CHUNK) * 10240 + nt * 1024 +        \
                                   lane * 16);                               \
  }
#define WISS8(BUF, HALF)                                                     \
  {                                                                          \
    _Pragma("unroll") for (int nt = 0; nt < 8; ++nt)                         \
        BUF[nt] = *(const bf16x8*)(Pb + 266240 + (HALF) * 8192 + nt * 1024 + \
                                   lane * 16);                               \
  }
#define MFMA10(BUF)                                                          \
  {                                                                          \
    _Pragma("unroll") for (int nt = 0; nt < 10; ++nt)                        \
        acc[nt] = __builtin_amdgcn_mfma_f32_16x16x32_bf16(af, BUF[nt],       \
                                                          acc[nt], 0, 0, 0); \
  }

// ---------------- Kernel Main: co-resident producer/consumer pipeline ------
__global__ __launch_bounds__(256, 2) void kMain(
    const float* __restrict__ signal, const float* __restrict__ comp,
    const unsigned short* __restrict__ Pseq,
    const float* __restrict__ bias1, const float* __restrict__ b1p,
    const float* __restrict__ b2p, const float* __restrict__ b3,
    unsigned short* __restrict__ csum, int* flags,
    float* __restrict__ out) {
  extern __shared__ char lds[];
  const int tid = threadIdx.x;

  if (blockIdx.x < 256) {
    // ================= PRODUCER: comp-sum for slab c =================
    const int c = (int)blockIdx.x;
    const f32x4* cp = (const f32x4*)comp;
    u32x2* op = (u32x2*)csum;
    for (int s = 0; s < 4; ++s) {
      const size_t base = (size_t)(c * 16384 + s * 4096) + tid;  // f32x4 units
      f32x4 a[16];
#pragma unroll
      for (int j = 0; j < 16; ++j) a[j] = cp[base + j * 256];
#pragma unroll
      for (int k = 1; k < 8; ++k) {
        f32x4 t0[16];
#pragma unroll
        for (int j = 0; j < 16; ++j)
          t0[j] = cp[base + (size_t)k * 4194304u + j * 256];
#pragma unroll
        for (int j = 0; j < 16; ++j) a[j] += t0[j];
      }
#pragma unroll
      for (int j = 0; j < 16; ++j) op[base + j * 256] = pack4(a[j]);
      __syncthreads();   // all waves' csum stores complete (vmcnt drain)
      if (tid == 0) {
        __threadfence();  // device-scope visibility of csum stores
        __hip_atomic_store(&flags[c * 4 + s], 1, __ATOMIC_RELEASE,
                           __HIP_MEMORY_SCOPE_AGENT);
      }
    }
  } else {
    // ================= CONSUMER: MLP for slab c =================
    const int c = (int)blockIdx.x - 256;
    const int wave = tid >> 6;
    const int lane = tid & 63;
    const int lhalf = lane >> 4;
    const int l16 = lane & 15;
    const int r2 = lane >> 5, c32 = lane & 31;
    char* act = lds + wave * 8192;
    const char* Pb = (const char*)Pseq;
    const int asw = (l16 & 7) << 4;

    for (int s = 0; s < 4; ++s) {
      const int row0 = c * 256 + s * 64 + wave * 16;

      // ---- signal: load 16 rows f32, pack -> act tile (cols 0..255 bf16) --
      {
        f32x4 sg[16];
        const f32x4* sp = (const f32x4*)signal;
#pragma unroll
        for (int r = 0; r < 16; ++r) sg[r] = sp[(size_t)(row0 + r) * 64 + lane];
#pragma unroll
        for (int r = 0; r < 16; ++r)
          *(u32x2*)(act + r * 512 + ((lane * 8) ^ ((r & 7) << 4))) =
              pack4(sg[r]);
      }

      bf16x8 wA[10], wB[10];
      WISS(wA, 0);                       // prefetch L1 chunk 0 (L2-resident)

      // ---- wait for producer sub-chunk ----
      {
        const int fi = c * 4 + s;
        while (__hip_atomic_load(&flags[fi], __ATOMIC_ACQUIRE,
                                 __HIP_MEMORY_SCOPE_AGENT) == 0)
          __builtin_amdgcn_s_sleep(16);
      }

      // ---- csum rows (fresh from producer; L3-hot) ----
      u16x8 cs[8];
#pragma unroll
      for (int j = 0; j < 8; ++j)
        cs[j] = *(const u16x8*)(csum + (size_t)(row0 + 2 * j + r2) * 256 +
                                c32 * 8);

      f32x4 acc[10];
#pragma unroll
      for (int i = 0; i < 10; ++i) acc[i] = f32x4{0.f, 0.f, 0.f, 0.f};

      // ---- L1 pass 1 (signal half), phases 0..7 ----
#pragma unroll
      for (int kk = 0; kk < 8; ++kk) {
        if (kk & 1) { WISS(wA, kk + 1); } else { WISS(wB, kk + 1); }
        bf16x8 af =
            *(const bf16x8*)(act + l16 * 512 + ((kk * 64 + lhalf * 16) ^ asw));
        if (kk & 1) { MFMA10(wB); } else { MFMA10(wA); }
      }

      // overwrite act tile with comp-sum (wave-local)
      asm volatile("" ::: "memory");
#pragma unroll
      for (int j = 0; j < 8; ++j) {
        const int rw = 2 * j + r2;
        *(u16x8*)(act + rw * 512 + ((c32 * 16) ^ ((rw & 7) << 4))) = cs[j];
      }
      asm volatile("" ::: "memory");

      // ---- L1 pass 2 (comp-sum half), phases 8..15 ----
#pragma unroll
      for (int kk = 8; kk < 16; ++kk) {
        if (kk & 1) { WISS(wA, kk + 1); } else { WISS(wB, kk + 1); }
        bf16x8 af = *(const bf16x8*)(act + l16 * 512 +
                                     (((kk - 8) * 64 + lhalf * 16) ^ asw));
        if (kk & 1) { MFMA10(wB); } else { MFMA10(wA); }
      }

      // bias + relu -> act
      {
        float bv[10];
#pragma unroll
        for (int nt = 0; nt < 10; ++nt) bv[nt] = bias1[nt * 16 + l16];
        asm volatile("" ::: "memory");
#pragma unroll
        for (int nt = 0; nt < 10; ++nt) {
#pragma unroll
          for (int r = 0; r < 4; ++r) {
            const int row = lhalf * 4 + r;
            float v = fmaxf(acc[nt][r] + bv[nt], 0.f);
            *(unsigned short*)(act + row * 512 +
                               (((nt * 16 + l16) * 2) ^ ((row & 7) << 4))) =
                f2bf(v);
          }
        }
        asm volatile("" ::: "memory");
      }

      // ---- hidden layers: chunks 16..20 (W1), 21..25 (W2) ----
      bf16x8 w4A[8], w4B[8];
#pragma unroll
      for (int L = 0; L < 2; ++L) {
        const float* hbias = L ? b2p : b1p;
#pragma unroll
        for (int i = 0; i < 10; ++i) acc[i] = f32x4{0.f, 0.f, 0.f, 0.f};
#pragma unroll
        for (int q = 0; q < 5; ++q) {
          const int cc = 16 + L * 5 + q;     // chunk in use; parity cc&1
          if (cc < 25) {
            if (cc & 1) { WISS(wA, cc + 1); } else { WISS(wB, cc + 1); }
          } else {
            WISS8(w4A, 0);                   // prefetch L4 half 0
          }
          bf16x8 af =
              *(const bf16x8*)(act + l16 * 512 + ((q * 64 + lhalf * 16) ^ asw));
          if (cc & 1) { MFMA10(wB); } else { MFMA10(wA); }
        }
        float bv[10];
#pragma unroll
        for (int nt = 0; nt < 10; ++nt) bv[nt] = hbias[nt * 16 + l16];
        asm volatile("" ::: "memory");
#pragma unroll
        for (int nt = 0; nt < 10; ++nt) {
#pragma unroll
          for (int r = 0; r < 4; ++r) {
            const int row = lhalf * 4 + r;
            float v = fmaxf(acc[nt][r] + bv[nt], 0.f);
            *(unsigned short*)(act + row * 512 +
                               (((nt * 16 + l16) * 2) ^ ((row & 7) << 4))) =
                f2bf(v);
          }
        }
        asm volatile("" ::: "memory");
      }

      // ---- layer 4: 10 half-phases (half h: chunk h>>1, frags (h&1)*8+i) --
      f32x4 a4[16];
#pragma unroll
      for (int i = 0; i < 16; ++i) a4[i] = f32x4{0.f, 0.f, 0.f, 0.f};
#pragma unroll
      for (int h = 0; h < 10; ++h) {
        if (h < 9) {
          if (h & 1) { WISS8(w4A, h + 1); } else { WISS8(w4B, h + 1); }
        }
        bf16x8 af = *(const bf16x8*)(act + l16 * 512 +
                                     (((h >> 1) * 64 + lhalf * 16) ^ asw));
#pragma unroll
        for (int i = 0; i < 8; ++i) {
          const int nt = (h & 1) * 8 + i;
          if (h & 1)
            a4[nt] = __builtin_amdgcn_mfma_f32_16x16x32_bf16(af, w4B[i],
                                                             a4[nt], 0, 0, 0);
          else
            a4[nt] = __builtin_amdgcn_mfma_f32_16x16x32_bf16(af, w4A[i],
                                                             a4[nt], 0, 0, 0);
        }
      }

      // ---- store ----
      float bv[16];
#pragma unroll
      for (int nt = 0; nt < 16; ++nt) bv[nt] = b3[nt * 16 + l16];
      float* op = out + (size_t)(row0 + lhalf * 4) * 256 + l16;
#pragma unroll
      for (int nt = 0; nt < 16; ++nt) {
#pragma unroll
        for (int r = 0; r < 4; ++r)
          op[(size_t)r * 256 + nt * 16] = a4[nt][r] + bv[nt];
      }
    }
  }
}

// ---------------- launcher ----------------
extern "C" void kernel_launch(void* const* d_in, const int* in_sizes, int n_in,
                              void* d_out, int out_size, void* d_ws, size_t ws_size,
                              hipStream_t stream) {
  const float* signal = (const float*)d_in[0];
  const float* comp   = (const float*)d_in[1];
  const float* Wm = (const float*)d_in[2];
  const float* bm = (const float*)d_in[3];
  const float* Wu = (const float*)d_in[4];
  const float* bu = (const float*)d_in[5];
  const float* W0 = (const float*)d_in[6];
  const float* b0 = (const float*)d_in[7];
  const float* W1 = (const float*)d_in[8];
  const float* b1 = (const float*)d_in[9];
  const float* W2 = (const float*)d_in[10];
  const float* b2 = (const float*)d_in[11];
  const float* W3 = (const float*)d_in[12];
  const float* b3 = (const float*)d_in[13];

  char* ws = (char*)d_ws;
  float* Wc    = (float*)(ws + 0);        // 33792 f32 (135168 B)
  float* bias1 = (float*)(ws + 135168);   // 160 f32
  float* b1p   = (float*)(ws + 135808);   // 160 f32
  float* b2p   = (float*)(ws + 136448);   // 160 f32
  // contiguous packed-weight sequence (uniform chunk offsets off P1):
  unsigned short* P1 = (unsigned short*)(ws + 137216);  // 81920 u16 (160KB)
  unsigned short* P2 = (unsigned short*)(ws + 301056);  // 25600 u16 (50KB)
  unsigned short* P3 = (unsigned short*)(ws + 352256);  // 25600 u16 (50KB)
  unsigned short* P4 = (unsigned short*)(ws + 403456);  // 40960 u16 (80KB)
  int* flags = (int*)(ws + 485376);                     // 1024 ints (4KB)
  unsigned short* csum = (unsigned short*)(ws + 489472); // [N,256] bf16 33.5MB

  hipLaunchKernelGGL(kP, dim3(133), dim3(256), 0, stream,
                     W0, Wu, Wm, bm, bu, b0, b1, b2, Wc, bias1, b1p, b2p,
                     flags);
  hipLaunchKernelGGL(kC, dim3(680), dim3(256), 0, stream,
                     W0, Wc, W1, W2, W3, P1, P2, P3, P4);
  hipLaunchKernelGGL(kMain, dim3(512), dim3(256), 32768, stream,
                     signal, comp, P1, bias1, b1p, b2p, b3, csum, flags,
                     (float*)d_out);
}

// Round 5
// 273.034 us; speedup vs baseline: 2.9305x; 2.9305x over previous
//
#include <hip/hip_runtime.h>
#include <hip/hip_bf16.h>

// PointProp for MI355X (gfx950) — R9.
//   kP: prep (Wc = W0r@Wu@Wm folded; bias chain)     kC: pack weights (bf16)
//   kD: fully-fused MLP with PER-COMPONENT L1 DECOMPOSITION.
//       csum@Wc^T = sum_k comp_k@Wc^T (linearity), so the csum half of L1
//       runs as 64 phases (8 Wc chunks x 8 components), each loading its
//       16x32 f32 A-fragment DIRECT from global (32B/lane coalesced),
//       cvt_pk -> bf16, MFMA into the same f32 acc. Signal half: same
//       direct-load pattern (8 phases). 72 of ~92 phases carry HBM traffic
//       -> the 537MB stream self-overlaps with all compute. No csum buffer,
//       no barriers, no cross-block sync (R8's agent-scope sync was 4x
//       slower than serial). Weights register-dbuf'd from L2, re-used
//       across the 8 k's per chunk (340KB L2 per wave).
//       Precision: bf16(comp_k) pre-sum vs bf16(csum) post-sum are
//       quadrature-equivalent (rel rounding error is scale-free).
// Math: out = L4(relu(L3(relu(L2(relu(sig@W0s^T + sum_k comp_k@Wc^T
//       + bias1)))))) with Wc = W0r@Wu@Wm folded, H padded 132->160.

typedef float  f32x4  __attribute__((ext_vector_type(4)));
typedef __bf16 bf16x8 __attribute__((ext_vector_type(8)));
typedef unsigned int   u32x4 __attribute__((ext_vector_type(4)));

__device__ __forceinline__ unsigned short f2bf(float f) {
  unsigned int u = __builtin_bit_cast(unsigned int, f);
  u += 0x7fffu + ((u >> 16) & 1u);   // RNE
  return (unsigned short)(u >> 16);
}

// 8 f32 -> bf16x8 via v_cvt_pk_bf16_f32 (RNE), 4 insts
__device__ __forceinline__ bf16x8 cvt8(f32x4 a, f32x4 b) {
  unsigned r0, r1, r2, r3;
  asm("v_cvt_pk_bf16_f32 %0, %1, %2" : "=v"(r0) : "v"(a[0]), "v"(a[1]));
  asm("v_cvt_pk_bf16_f32 %0, %1, %2" : "=v"(r1) : "v"(a[2]), "v"(a[3]));
  asm("v_cvt_pk_bf16_f32 %0, %1, %2" : "=v"(r2) : "v"(b[0]), "v"(b[1]));
  asm("v_cvt_pk_bf16_f32 %0, %1, %2" : "=v"(r3) : "v"(b[2]), "v"(b[3]));
  u32x4 r{r0, r1, r2, r3};
  return __builtin_bit_cast(bf16x8, r);
}

// ---------------- Kernel P: all prep (Wc, bias1, padded biases) -------------
__global__ __launch_bounds__(256) void kP(
    const float* __restrict__ W0, const float* __restrict__ Wu,
    const float* __restrict__ Wm, const float* __restrict__ bm,
    const float* __restrict__ bu, const float* __restrict__ b0,
    const float* __restrict__ b1, const float* __restrict__ b2,
    float* __restrict__ Wc, float* __restrict__ bias1,
    float* __restrict__ b1p, float* __restrict__ b2p) {
  const int b = blockIdx.x;
  const int d = threadIdx.x;
  if (b < 132) {
    __shared__ float u[256];
    const int h = b;
    float s = 0.f;
#pragma unroll 8
    for (int i = 0; i < 256; ++i) s += W0[h * 512 + 256 + i] * Wu[i * 256 + d];
    u[d] = s;
    __syncthreads();
    float s2 = 0.f;
#pragma unroll 8
    for (int j = 0; j < 256; ++j) s2 += u[j] * Wm[j * 256 + d];
    Wc[h * 256 + d] = s2;
  } else {
    __shared__ float bml[256];
    __shared__ float rbl[256];
    bml[d] = bm[d];
    __syncthreads();
    {
      const f32x4* wr = (const f32x4*)(Wu + d * 256);
      const f32x4* bm4 = (const f32x4*)bml;
      float s = 0.f;
#pragma unroll 8
      for (int i = 0; i < 64; ++i) {
        f32x4 w = wr[i], v = bm4[i];
        s += w[0] * v[0] + w[1] * v[1] + w[2] * v[2] + w[3] * v[3];
      }
      rbl[d] = 8.f * s + bu[d];
    }
    __syncthreads();
    if (d < 160) {
      float v = 0.f;
      if (d < 132) {
        float s = 0.f;
#pragma unroll 8
        for (int j = 0; j < 256; ++j) s += W0[d * 512 + 256 + j] * rbl[j];
        v = b0[d] + s;
      }
      bias1[d] = v;
      b1p[d] = (d < 132) ? b1[d] : 0.f;
      b2p[d] = (d < 132) ? b2[d] : 0.f;
    }
  }
}

// ---------------- Kernel C: pack weights to MFMA B-frag order (bf16) --------
// Chunk (kk,nt) = 1024B: lane l holds B[kk*32+(l>>4)*8+j][nt*16+(l&15)], j=0..7.
// L1: K=512,N=160; L2/L3: 160x160; L4: 160x256. P1..P4 CONTIGUOUS in ws
// (uniform chunk offset: chunk c at c*10240 for c=0..25; L4 halves at
//  266240 + h*8192).
__global__ __launch_bounds__(256) void kC(
    const float* __restrict__ W0, const float* __restrict__ Wc,
    const float* __restrict__ W1, const float* __restrict__ W2,
    const float* __restrict__ W3,
    unsigned short* __restrict__ P1, unsigned short* __restrict__ P2,
    unsigned short* __restrict__ P3, unsigned short* __restrict__ P4) {
  int e = blockIdx.x * 256 + threadIdx.x;
  if (e >= 174080) return;
  unsigned short* dst; int NT, rel, mode;
  if (e < 81920)       { dst = P1; NT = 10; rel = e;          mode = 0; }
  else if (e < 107520) { dst = P2; NT = 10; rel = e - 81920;  mode = 1; }
  else if (e < 133120) { dst = P3; NT = 10; rel = e - 107520; mode = 2; }
  else                 { dst = P4; NT = 16; rel = e - 133120; mode = 3; }
  int chunk = rel >> 9, q = rel & 511;
  int lane = q >> 3, j = q & 7;
  int kk = chunk / NT, nt = chunk - kk * NT;
  int k = kk * 32 + (lane >> 4) * 8 + j;
  int n = nt * 16 + (lane & 15);
  float v = 0.f;
  if (mode == 0) {
    if (n < 132) v = (k < 256) ? W0[n * 512 + k] : Wc[n * 256 + (k - 256)];
  } else if (mode == 1) {
    if (n < 132 && k < 132) v = W1[n * 132 + k];
  } else if (mode == 2) {
    if (n < 132 && k < 132) v = W2[n * 132 + k];
  } else {
    if (k < 132) v = W3[n * 132 + k];
  }
  dst[rel] = f2bf(v);
}

// ---- per-wave weight issue (direct L2 -> VGPR, coalesced 1KB per frag) ----
#define WISS(BUF, CHUNK)                                                     \
  {                                                                          \
    _Pragma("unroll") for (int nt = 0; nt < 10; ++nt)                        \
        BUF[nt] = *(const bf16x8*)(Pb + (CHUNK) * 10240 + nt * 1024 +        \
                                   lane * 16);                               \
  }
#define WISS8(BUF, HALF)                                                     \
  {                                                                          \
    _Pragma("unroll") for (int nt = 0; nt < 8; ++nt)                         \
        BUF[nt] = *(const bf16x8*)(Pb + 266240 + (HALF) * 8192 + nt * 1024 + \
                                   lane * 16);                               \
  }
#define MFMA10(BUF)                                                          \
  {                                                                          \
    _Pragma("unroll") for (int nt = 0; nt < 10; ++nt)                        \
        acc[nt] = __builtin_amdgcn_mfma_f32_16x16x32_bf16(af, BUF[nt],       \
                                                          acc[nt], 0, 0, 0); \
  }

// ---------------- Kernel D: fused MLP, per-component L1 ---------------------
// grid 1024 x 256; wave owns 16 rows; NO barriers, NO inter-block sync.
// L1 = 72 phases: p<8 sig chunk p; p>=8 comp(kk=(p-8)>>3, k=(p-8)&7) vs
// chunk 8+kk. Each phase: [weight prefetch (kk boundary)] [next A loads]
// [cvt8] [10 MFMA]. A-frag loaded direct from global: lane reads rows
// row0+l16, 8 consecutive f32 at col kk*32+lhalf*8 (2x dwordx4, coalesced
// 128B per 4-lane group). Hidden/L4: as R7 (register weight dbuf, act LDS).
__global__ __launch_bounds__(256, 2) void kD(
    const float* __restrict__ signal, const float* __restrict__ comp,
    const unsigned short* __restrict__ Pseq,
    const float* __restrict__ bias1, const float* __restrict__ b1p,
    const float* __restrict__ b2p, const float* __restrict__ b3,
    float* __restrict__ out) {
  extern __shared__ char lds[];
  const int tid = threadIdx.x;
  const int wave = tid >> 6;
  const int lane = tid & 63;
  const int lhalf = lane >> 4;
  const int l16 = lane & 15;
  char* act = lds + wave * 8192;
  const char* Pb = (const char*)Pseq;
  const int row0 = ((int)blockIdx.x * 4 + wave) * 16;
  const int asw = (l16 & 7) << 4;

  const f32x4* sp = (const f32x4*)signal;
  const f32x4* cp = (const f32x4*)comp;
  // f32x4-unit base for this lane's A-frag rows: row (row0+l16), col lhalf*8
  const size_t abase = (size_t)(row0 + l16) * 64 + lhalf * 2;

  bf16x8 wA[10], wB[10];
  WISS(wA, 0);                         // L1 chunk 0 (even -> wA)

  f32x4 c0 = sp[abase], c1 = sp[abase + 1];   // sig phase 0
  f32x4 n0, n1;

  f32x4 acc[10];
#pragma unroll
  for (int i = 0; i < 10; ++i) acc[i] = f32x4{0.f, 0.f, 0.f, 0.f};

  // ---- L1: 72 phases (8 sig + 64 comp) ----
#pragma unroll
  for (int p = 0; p < 72; ++p) {
    // weight prefetch into the off buffer (parity of chunk index)
    if (p < 8) {
      const int cn = p + 1;                        // chunks 1..8
      if (cn & 1) { WISS(wB, cn); } else { WISS(wA, cn); }
    } else if (((p - 8) & 7) == 0 && p >= 8) {
      const int cn = 9 + ((p - 8) >> 3);           // chunks 9..16
      if (cn & 1) { WISS(wB, cn); } else { WISS(wA, cn); }
    }
    // issue next phase's A loads (depth-1 rolling prefetch)
    if (p + 1 < 8) {
      n0 = sp[abase + (size_t)(p + 1) * 8];
      n1 = sp[abase + (size_t)(p + 1) * 8 + 1];
    } else if (p + 1 < 72) {
      const int q = p + 1 - 8, kkq = q >> 3, kq = q & 7;
      const size_t ci = (size_t)kq * 4194304u + abase + (size_t)kkq * 8;
      n0 = cp[ci];
      n1 = cp[ci + 1];
    }
    // convert current A-frag and multiply
    bf16x8 af = cvt8(c0, c1);
    const int cur = (p < 8) ? p : (8 + ((p - 8) >> 3));
    if (cur & 1) { MFMA10(wB); } else { MFMA10(wA); }
    c0 = n0;
    c1 = n1;
  }

  // ---- bias + relu -> act tile (bf16, XOR-swizzled A-frag layout) ----
  {
    float bv[10];
#pragma unroll
    for (int nt = 0; nt < 10; ++nt) bv[nt] = bias1[nt * 16 + l16];
    asm volatile("" ::: "memory");
#pragma unroll
    for (int nt = 0; nt < 10; ++nt) {
#pragma unroll
      for (int r = 0; r < 4; ++r) {
        const int row = lhalf * 4 + r;
        float v = fmaxf(acc[nt][r] + bv[nt], 0.f);
        *(unsigned short*)(act + row * 512 +
                           (((nt * 16 + l16) * 2) ^ ((row & 7) << 4))) = f2bf(v);
      }
    }
    asm volatile("" ::: "memory");
  }

  // ---- hidden layers: chunks 16..20 (W1), 21..25 (W2) ----
  bf16x8 w4A[8], w4B[8];
#pragma unroll
  for (int L = 0; L < 2; ++L) {
    const float* hbias = L ? b2p : b1p;
#pragma unroll
    for (int i = 0; i < 10; ++i) acc[i] = f32x4{0.f, 0.f, 0.f, 0.f};
#pragma unroll
    for (int qq = 0; qq < 5; ++qq) {
      const int cc = 16 + L * 5 + qq;      // chunk in use; parity cc&1
      if (cc < 25) {
        if (cc & 1) { WISS(wA, cc + 1); } else { WISS(wB, cc + 1); }
      } else {
        WISS8(w4A, 0);                     // prefetch L4 half 0
      }
      bf16x8 af =
          *(const bf16x8*)(act + l16 * 512 + ((qq * 64 + lhalf * 16) ^ asw));
      if (cc & 1) { MFMA10(wB); } else { MFMA10(wA); }
    }
    float bv[10];
#pragma unroll
    for (int nt = 0; nt < 10; ++nt) bv[nt] = hbias[nt * 16 + l16];
    asm volatile("" ::: "memory");
#pragma unroll
    for (int nt = 0; nt < 10; ++nt) {
#pragma unroll
      for (int r = 0; r < 4; ++r) {
        const int row = lhalf * 4 + r;
        float v = fmaxf(acc[nt][r] + bv[nt], 0.f);
        *(unsigned short*)(act + row * 512 +
                           (((nt * 16 + l16) * 2) ^ ((row & 7) << 4))) = f2bf(v);
      }
    }
    asm volatile("" ::: "memory");
  }

  // ---- layer 4: 10 half-phases (half h: chunk h>>1, frags (h&1)*8 + i) ----
  f32x4 a4[16];
#pragma unroll
  for (int i = 0; i < 16; ++i) a4[i] = f32x4{0.f, 0.f, 0.f, 0.f};
#pragma unroll
  for (int h = 0; h < 10; ++h) {
    if (h < 9) {
      if (h & 1) { WISS8(w4A, h + 1); } else { WISS8(w4B, h + 1); }
    }
    bf16x8 af = *(const bf16x8*)(act + l16 * 512 +
                                 (((h >> 1) * 64 + lhalf * 16) ^ asw));
#pragma unroll
    for (int i = 0; i < 8; ++i) {
      const int nt = (h & 1) * 8 + i;
      if (h & 1)
        a4[nt] = __builtin_amdgcn_mfma_f32_16x16x32_bf16(af, w4B[i], a4[nt],
                                                         0, 0, 0);
      else
        a4[nt] = __builtin_amdgcn_mfma_f32_16x16x32_bf16(af, w4A[i], a4[nt],
                                                         0, 0, 0);
    }
  }

  // ---- store ----
  float bv[16];
#pragma unroll
  for (int nt = 0; nt < 16; ++nt) bv[nt] = b3[nt * 16 + l16];
  float* op = out + (size_t)(row0 + lhalf * 4) * 256 + l16;
#pragma unroll
  for (int nt = 0; nt < 16; ++nt) {
#pragma unroll
    for (int r = 0; r < 4; ++r)
      op[(size_t)r * 256 + nt * 16] = a4[nt][r] + bv[nt];
  }
}

// ---------------- launcher ----------------
extern "C" void kernel_launch(void* const* d_in, const int* in_sizes, int n_in,
                              void* d_out, int out_size, void* d_ws, size_t ws_size,
                              hipStream_t stream) {
  const float* signal = (const float*)d_in[0];
  const float* comp   = (const float*)d_in[1];
  const float* Wm = (const float*)d_in[2];
  const float* bm = (const float*)d_in[3];
  const float* Wu = (const float*)d_in[4];
  const float* bu = (const float*)d_in[5];
  const float* W0 = (const float*)d_in[6];
  const float* b0 = (const float*)d_in[7];
  const float* W1 = (const float*)d_in[8];
  const float* b1 = (const float*)d_in[9];
  const float* W2 = (const float*)d_in[10];
  const float* b2 = (const float*)d_in[11];
  const float* W3 = (const float*)d_in[12];
  const float* b3 = (const float*)d_in[13];

  char* ws = (char*)d_ws;
  float* Wc    = (float*)(ws + 0);        // 33792 f32 (135168 B)
  float* bias1 = (float*)(ws + 135168);   // 160 f32
  float* b1p   = (float*)(ws + 135808);   // 160 f32
  float* b2p   = (float*)(ws + 136448);   // 160 f32
  // contiguous packed-weight sequence (uniform chunk offsets off P1):
  unsigned short* P1 = (unsigned short*)(ws + 137216);  // 81920 u16 (160KB)
  unsigned short* P2 = (unsigned short*)(ws + 301056);  // 25600 u16 (50KB)
  unsigned short* P3 = (unsigned short*)(ws + 352256);  // 25600 u16 (50KB)
  unsigned short* P4 = (unsigned short*)(ws + 403456);  // 40960 u16 (80KB)

  hipLaunchKernelGGL(kP, dim3(133), dim3(256), 0, stream,
                     W0, Wu, Wm, bm, bu, b0, b1, b2, Wc, bias1, b1p, b2p);
  hipLaunchKernelGGL(kC, dim3(680), dim3(256), 0, stream,
                     W0, Wc, W1, W2, W3, P1, P2, P3, P4);
  hipLaunchKernelGGL(kD, dim3(1024), dim3(256), 32768, stream,
                     signal, comp, P1, bias1, b1p, b2p, b3, (float*)d_out);
}

// Round 6
// 187.161 us; speedup vs baseline: 4.2751x; 1.4588x over previous
//
#include <hip/hip_runtime.h>
#include <hip/hip_bf16.h>

// PointProp for MI355X (gfx950) — R10.
//   kA: prep1 + comp-sum (k-serial, R4 verbatim — BW-bound ~90us)
//   kB: prep2 (R4 verbatim)   kC: pack weights to MFMA frag order (verbatim)
//   kD: REBUILT. Diagnosis across R4-R9: kD was LDS-pipe-bound (~700
//       ds_read_b128/wave for B-frags = ~50us/CU). R10: B-frags in REGISTERS
//       (WISS direct from L2), each weight fetch shared by TWO 16-row groups
//       (32 rows/wave -> 2048 waves -> 700MB L2, ~20us, overlappable).
//       LDS used only for the A-side transpose (2 ds_reads/phase + act
//       writes). No barriers (wave-private act tiles). L4 split into two
//       N-128 halves to cap accumulator VGPRs at 64.
// Math: out = L4(relu(L3(relu(L2(relu(sig@W0s^T + csum@Wc^T + bias1))))))
// with Wc = W0r@Wu@Wm folded (linearity), H padded 132->160.

typedef float  f32x4  __attribute__((ext_vector_type(4)));
typedef __bf16 bf16x8 __attribute__((ext_vector_type(8)));
typedef unsigned int   u32x2 __attribute__((ext_vector_type(2)));
typedef unsigned short u16x8 __attribute__((ext_vector_type(8)));

__device__ __forceinline__ unsigned short f2bf(float f) {
  unsigned int u = __builtin_bit_cast(unsigned int, f);
  u += 0x7fffu + ((u >> 16) & 1u);   // RNE
  return (unsigned short)(u >> 16);
}

__device__ __forceinline__ u32x2 pack4(f32x4 v) {
  u32x2 r;
  r[0] = (unsigned)f2bf(v[0]) | ((unsigned)f2bf(v[1]) << 16);
  r[1] = (unsigned)f2bf(v[2]) | ((unsigned)f2bf(v[3]) << 16);
  return r;
}

__device__ __forceinline__ float wave_reduce(float s) {
#pragma unroll
  for (int m = 32; m > 0; m >>= 1) s += __shfl_xor(s, m, 64);
  return s;
}

// ---------------- Kernel A: prep1 (U, rb) + comp-sum (k-serial) -------------
// blocks 0..131: U = W0r@Wu ; 132..195: rb = 8*(Wu@bm)+bu
// blocks 196..2243: block cb owns rows [cb*32, cb*32+32); k-serial.
__global__ __launch_bounds__(256) void kA(const float* __restrict__ comp,
                                          const float* __restrict__ W0,
                                          const float* __restrict__ Wu,
                                          const float* __restrict__ bm,
                                          const float* __restrict__ bu,
                                          float* __restrict__ U,
                                          float* __restrict__ rb,
                                          unsigned short* __restrict__ csum) {
  const int b = blockIdx.x;
  if (b >= 196) {
    const int cb = b - 196;                       // 0..2047
    const int t = threadIdx.x;
    const f32x4* cp = (const f32x4*)comp;
    const size_t base = (size_t)cb * 2048 + t;    // f32x4 units
    f32x4 a[8];
#pragma unroll
    for (int j = 0; j < 8; ++j) a[j] = cp[base + j * 256];
#pragma unroll
    for (int k = 1; k < 8; ++k) {
      f32x4 t0[8];
#pragma unroll
      for (int j = 0; j < 8; ++j) t0[j] = cp[base + (size_t)k * 4194304u + j * 256];
#pragma unroll
      for (int j = 0; j < 8; ++j) a[j] += t0[j];
    }
    u32x2* op = (u32x2*)csum;
#pragma unroll
    for (int j = 0; j < 8; ++j) op[base + j * 256] = pack4(a[j]);
  } else if (b < 132) {
    const int h = b, d = threadIdx.x;
    float s = 0.f;
#pragma unroll 8
    for (int i = 0; i < 256; ++i) s += W0[h * 512 + 256 + i] * Wu[i * 256 + d];
    U[h * 256 + d] = s;
  } else {
    const int t = (b - 132) * 4 + (threadIdx.x >> 6);   // 0..255
    const int lane = threadIdx.x & 63;
    f32x4 w = ((const f32x4*)(Wu + t * 256))[lane];
    f32x4 v = ((const f32x4*)bm)[lane];
    float s = w[0] * v[0] + w[1] * v[1] + w[2] * v[2] + w[3] * v[3];
    s = wave_reduce(s);
    if (lane == 0) rb[t] = 8.f * s + bu[t];
  }
}

// ---------------- Kernel B: prep2 (Wc, bias1, padded biases) ----------------
__global__ __launch_bounds__(256) void kB(const float* __restrict__ U,
                                          const float* __restrict__ Wm,
                                          const float* __restrict__ W0,
                                          const float* __restrict__ rb,
                                          const float* __restrict__ b0,
                                          const float* __restrict__ b1,
                                          const float* __restrict__ b2,
                                          float* __restrict__ Wc,
                                          float* __restrict__ bias1,
                                          float* __restrict__ b1p,
                                          float* __restrict__ b2p) {
  const int b = blockIdx.x;
  if (b < 132) {
    const int h = b, d = threadIdx.x;
    float s = 0.f;
#pragma unroll 8
    for (int j = 0; j < 256; ++j) s += U[h * 256 + j] * Wm[j * 256 + d];
    Wc[h * 256 + d] = s;
  } else {
    const int t = (b - 132) * 4 + (threadIdx.x >> 6);   // 0..159
    const int lane = threadIdx.x & 63;
    float v = 0.f;
    if (t < 132) {
      f32x4 w = ((const f32x4*)(W0 + t * 512 + 256))[lane];
      f32x4 r4 = ((const f32x4*)rb)[lane];
      float s = w[0] * r4[0] + w[1] * r4[1] + w[2] * r4[2] + w[3] * r4[3];
      s = wave_reduce(s);
      v = b0[t] + s;
    }
    if (lane == 0) {
      bias1[t] = v;
      b1p[t] = (t < 132) ? b1[t] : 0.f;
      b2p[t] = (t < 132) ? b2[t] : 0.f;
    }
  }
}

// ---------------- Kernel C: pack weights to MFMA B-frag order (bf16) --------
// Chunk (kk,nt) = 1024B: lane l holds B[kk*32+(l>>4)*8+j][nt*16+(l&15)], j=0..7.
// L1: K=512,N=160; L2/L3: 160x160; L4: 160x256. P1..P4 CONTIGUOUS in ws.
__global__ __launch_bounds__(256) void kC(
    const float* __restrict__ W0, const float* __restrict__ Wc,
    const float* __restrict__ W1, const float* __restrict__ W2,
    const float* __restrict__ W3,
    unsigned short* __restrict__ P1, unsigned short* __restrict__ P2,
    unsigned short* __restrict__ P3, unsigned short* __restrict__ P4) {
  int e = blockIdx.x * 256 + threadIdx.x;
  if (e >= 174080) return;
  unsigned short* dst; int NT, rel, mode;
  if (e < 81920)       { dst = P1; NT = 10; rel = e;          mode = 0; }
  else if (e < 107520) { dst = P2; NT = 10; rel = e - 81920;  mode = 1; }
  else if (e < 133120) { dst = P3; NT = 10; rel = e - 107520; mode = 2; }
  else                 { dst = P4; NT = 16; rel = e - 133120; mode = 3; }
  int chunk = rel >> 9, q = rel & 511;
  int lane = q >> 3, j = q & 7;
  int kk = chunk / NT, nt = chunk - kk * NT;
  int k = kk * 32 + (lane >> 4) * 8 + j;
  int n = nt * 16 + (lane & 15);
  float v = 0.f;
  if (mode == 0) {
    if (n < 132) v = (k < 256) ? W0[n * 512 + k] : Wc[n * 256 + (k - 256)];
  } else if (mode == 1) {
    if (n < 132 && k < 132) v = W1[n * 132 + k];
  } else if (mode == 2) {
    if (n < 132 && k < 132) v = W2[n * 132 + k];
  } else {
    if (k < 132) v = W3[n * 132 + k];
  }
  dst[rel] = f2bf(v);
}

// ---- per-wave weight issue (direct L2 -> VGPR, coalesced 1KB per frag) ----
// chunks 0..25 contiguous at c*10240; L4 chunk (h,kk) 8-frag group at
// 266240 + kk*16384 + h*8192.
#define WISS(BUF, CHUNK)                                                     \
  {                                                                          \
    _Pragma("unroll") for (int nt = 0; nt < 10; ++nt)                        \
        BUF[nt] = *(const bf16x8*)(Pb + (CHUNK) * 10240 + nt * 1024 +        \
                                   lane * 16);                               \
  }
#define WISS8L4(BUF, Q)                                                      \
  {                                                                          \
    _Pragma("unroll") for (int nt = 0; nt < 8; ++nt)                         \
        BUF[nt] = *(const bf16x8*)(Pb + 266240 + ((Q) % 5) * 16384 +         \
                                   ((Q) / 5) * 8192 + nt * 1024 + lane * 16);\
  }
#define MFMA10(ACC, BUF, AF)                                                 \
  {                                                                          \
    _Pragma("unroll") for (int nt = 0; nt < 10; ++nt)                        \
        ACC[nt] = __builtin_amdgcn_mfma_f32_16x16x32_bf16(AF, BUF[nt],       \
                                                          ACC[nt], 0, 0, 0); \
  }

// ---------------- Kernel D: 4-layer MLP, 32 rows/wave, register weights -----
// grid 512 x 256; wave owns 32 rows as two 16-row groups (act0/act1, 8KB
// each, wave-private, XOR-swizzled). One WISS feeds both groups' MFMAs.
__global__ __launch_bounds__(256, 2) void kD(
    const float* __restrict__ signal, const unsigned short* __restrict__ csum,
    const unsigned short* __restrict__ Pseq,
    const float* __restrict__ bias1, const float* __restrict__ b1p,
    const float* __restrict__ b2p, const float* __restrict__ b3,
    float* __restrict__ out) {
  extern __shared__ char lds[];
  const int tid = threadIdx.x;
  const int wave = tid >> 6;
  const int lane = tid & 63;
  const int lhalf = lane >> 4;
  const int l16 = lane & 15;
  const int r2 = lane >> 5, c32 = lane & 31;
  char* act0 = lds + wave * 16384;
  char* act1 = act0 + 8192;
  const char* Pb = (const char*)Pseq;
  const int row0 = ((int)blockIdx.x * 4 + wave) * 32;
  const int asw = (l16 & 7) << 4;
  const f32x4* sp = (const f32x4*)signal;

  // ---- prologue: signal -> act tiles (one group at a time: caps VGPRs) ----
  {
    f32x4 sg[16];
#pragma unroll
    for (int r = 0; r < 16; ++r) sg[r] = sp[(size_t)(row0 + r) * 64 + lane];
#pragma unroll
    for (int r = 0; r < 16; ++r)
      *(u32x2*)(act0 + r * 512 + ((lane * 8) ^ ((r & 7) << 4))) = pack4(sg[r]);
  }
  {
    f32x4 sg[16];
#pragma unroll
    for (int r = 0; r < 16; ++r)
      sg[r] = sp[(size_t)(row0 + 16 + r) * 64 + lane];
#pragma unroll
    for (int r = 0; r < 16; ++r)
      *(u32x2*)(act1 + r * 512 + ((lane * 8) ^ ((r & 7) << 4))) = pack4(sg[r]);
  }

  // csum for both groups (issued early; consumed at pass-2 switch)
  u16x8 cs0[8], cs1[8];
#pragma unroll
  for (int j = 0; j < 8; ++j)
    cs0[j] = *(const u16x8*)(csum + (size_t)(row0 + 2 * j + r2) * 256 + c32 * 8);
#pragma unroll
  for (int j = 0; j < 8; ++j)
    cs1[j] =
        *(const u16x8*)(csum + (size_t)(row0 + 16 + 2 * j + r2) * 256 + c32 * 8);

  bf16x8 wA[10], wB[10];
  WISS(wA, 0);

  f32x4 acc0[10], acc1[10];
#pragma unroll
  for (int i = 0; i < 10; ++i) {
    acc0[i] = f32x4{0.f, 0.f, 0.f, 0.f};
    acc1[i] = f32x4{0.f, 0.f, 0.f, 0.f};
  }

  // ---- L1 pass 1 (signal half), chunks 0..7 ----
#pragma unroll
  for (int kk = 0; kk < 8; ++kk) {
    if ((kk + 1) & 1) { WISS(wB, kk + 1); } else { WISS(wA, kk + 1); }
    bf16x8 af0 =
        *(const bf16x8*)(act0 + l16 * 512 + ((kk * 64 + lhalf * 16) ^ asw));
    bf16x8 af1 =
        *(const bf16x8*)(act1 + l16 * 512 + ((kk * 64 + lhalf * 16) ^ asw));
    if (kk & 1) {
      MFMA10(acc0, wB, af0); MFMA10(acc1, wB, af1);
    } else {
      MFMA10(acc0, wA, af0); MFMA10(acc1, wA, af1);
    }
  }

  // overwrite act tiles with comp-sum (wave-local)
  asm volatile("" ::: "memory");
#pragma unroll
  for (int j = 0; j < 8; ++j) {
    const int rw = 2 * j + r2;
    *(u16x8*)(act0 + rw * 512 + ((c32 * 16) ^ ((rw & 7) << 4))) = cs0[j];
    *(u16x8*)(act1 + rw * 512 + ((c32 * 16) ^ ((rw & 7) << 4))) = cs1[j];
  }
  asm volatile("" ::: "memory");

  // ---- L1 pass 2 (comp-sum half), chunks 8..15 ----
#pragma unroll
  for (int kk = 8; kk < 16; ++kk) {
    if ((kk + 1) & 1) { WISS(wB, kk + 1); } else { WISS(wA, kk + 1); }
    bf16x8 af0 = *(const bf16x8*)(act0 + l16 * 512 +
                                  (((kk - 8) * 64 + lhalf * 16) ^ asw));
    bf16x8 af1 = *(const bf16x8*)(act1 + l16 * 512 +
                                  (((kk - 8) * 64 + lhalf * 16) ^ asw));
    if (kk & 1) {
      MFMA10(acc0, wB, af0); MFMA10(acc1, wB, af1);
    } else {
      MFMA10(acc0, wA, af0); MFMA10(acc1, wA, af1);
    }
  }

  // bias + relu -> act tiles
  {
    float bv[10];
#pragma unroll
    for (int nt = 0; nt < 10; ++nt) bv[nt] = bias1[nt * 16 + l16];
    asm volatile("" ::: "memory");
#pragma unroll
    for (int nt = 0; nt < 10; ++nt) {
#pragma unroll
      for (int r = 0; r < 4; ++r) {
        const int row = lhalf * 4 + r;
        const int off = (((nt * 16 + l16) * 2) ^ ((row & 7) << 4));
        float v0 = fmaxf(acc0[nt][r] + bv[nt], 0.f);
        float v1 = fmaxf(acc1[nt][r] + bv[nt], 0.f);
        *(unsigned short*)(act0 + row * 512 + off) = f2bf(v0);
        *(unsigned short*)(act1 + row * 512 + off) = f2bf(v1);
      }
    }
    asm volatile("" ::: "memory");
  }

  // ---- hidden layers: chunks 16..20 (W1), 21..25 (W2) ----
  bf16x8 w4A[8], w4B[8];
#pragma unroll
  for (int L = 0; L < 2; ++L) {
    const float* hbias = L ? b2p : b1p;
#pragma unroll
    for (int i = 0; i < 10; ++i) {
      acc0[i] = f32x4{0.f, 0.f, 0.f, 0.f};
      acc1[i] = f32x4{0.f, 0.f, 0.f, 0.f};
    }
#pragma unroll
    for (int qq = 0; qq < 5; ++qq) {
      const int cc = 16 + L * 5 + qq;      // chunk in use (even->wA, odd->wB)
      if (cc < 25) {
        if (cc & 1) { WISS(wA, cc + 1); } else { WISS(wB, cc + 1); }
      } else {
        WISS8L4(w4A, 0);                   // prefetch L4 q=0
      }
      bf16x8 af0 =
          *(const bf16x8*)(act0 + l16 * 512 + ((qq * 64 + lhalf * 16) ^ asw));
      bf16x8 af1 =
          *(const bf16x8*)(act1 + l16 * 512 + ((qq * 64 + lhalf * 16) ^ asw));
      if (cc & 1) {
        MFMA10(acc0, wB, af0); MFMA10(acc1, wB, af1);
      } else {
        MFMA10(acc0, wA, af0); MFMA10(acc1, wA, af1);
      }
    }
    float bv[10];
#pragma unroll
    for (int nt = 0; nt < 10; ++nt) bv[nt] = hbias[nt * 16 + l16];
    asm volatile("" ::: "memory");
#pragma unroll
    for (int nt = 0; nt < 10; ++nt) {
#pragma unroll
      for (int r = 0; r < 4; ++r) {
        const int row = lhalf * 4 + r;
        const int off = (((nt * 16 + l16) * 2) ^ ((row & 7) << 4));
        float v0 = fmaxf(acc0[nt][r] + bv[nt], 0.f);
        float v1 = fmaxf(acc1[nt][r] + bv[nt], 0.f);
        *(unsigned short*)(act0 + row * 512 + off) = f2bf(v0);
        *(unsigned short*)(act1 + row * 512 + off) = f2bf(v1);
      }
    }
    asm volatile("" ::: "memory");
  }

  // ---- layer 4: two N-128 halves h=0,1; q = h*5+kk (even->w4A, odd->w4B) --
#pragma unroll
  for (int h = 0; h < 2; ++h) {
    f32x4 a40[8], a41[8];
#pragma unroll
    for (int i = 0; i < 8; ++i) {
      a40[i] = f32x4{0.f, 0.f, 0.f, 0.f};
      a41[i] = f32x4{0.f, 0.f, 0.f, 0.f};
    }
#pragma unroll
    for (int kk = 0; kk < 5; ++kk) {
      const int q = h * 5 + kk;
      if (q < 9) {
        if (q & 1) { WISS8L4(w4A, q + 1); } else { WISS8L4(w4B, q + 1); }
      }
      bf16x8 af0 =
          *(const bf16x8*)(act0 + l16 * 512 + ((kk * 64 + lhalf * 16) ^ asw));
      bf16x8 af1 =
          *(const bf16x8*)(act1 + l16 * 512 + ((kk * 64 + lhalf * 16) ^ asw));
#pragma unroll
      for (int i = 0; i < 8; ++i) {
        if (q & 1) {
          a40[i] = __builtin_amdgcn_mfma_f32_16x16x32_bf16(af0, w4B[i], a40[i],
                                                           0, 0, 0);
          a41[i] = __builtin_amdgcn_mfma_f32_16x16x32_bf16(af1, w4B[i], a41[i],
                                                           0, 0, 0);
        } else {
          a40[i] = __builtin_amdgcn_mfma_f32_16x16x32_bf16(af0, w4A[i], a40[i],
                                                           0, 0, 0);
          a41[i] = __builtin_amdgcn_mfma_f32_16x16x32_bf16(af1, w4A[i], a41[i],
                                                           0, 0, 0);
        }
      }
    }
    // store this half for both groups
    float bv[8];
#pragma unroll
    for (int i = 0; i < 8; ++i) bv[i] = b3[(h * 8 + i) * 16 + l16];
    float* op0 = out + (size_t)(row0 + lhalf * 4) * 256 + h * 128 + l16;
    float* op1 = out + (size_t)(row0 + 16 + lhalf * 4) * 256 + h * 128 + l16;
#pragma unroll
    for (int i = 0; i < 8; ++i) {
#pragma unroll
      for (int r = 0; r < 4; ++r) {
        op0[(size_t)r * 256 + i * 16] = a40[i][r] + bv[i];
        op1[(size_t)r * 256 + i * 16] = a41[i][r] + bv[i];
      }
    }
  }
}

// ---------------- launcher ----------------
extern "C" void kernel_launch(void* const* d_in, const int* in_sizes, int n_in,
                              void* d_out, int out_size, void* d_ws, size_t ws_size,
                              hipStream_t stream) {
  const float* signal = (const float*)d_in[0];
  const float* comp   = (const float*)d_in[1];
  const float* Wm = (const float*)d_in[2];
  const float* bm = (const float*)d_in[3];
  const float* Wu = (const float*)d_in[4];
  const float* bu = (const float*)d_in[5];
  const float* W0 = (const float*)d_in[6];
  const float* b0 = (const float*)d_in[7];
  const float* W1 = (const float*)d_in[8];
  const float* b1 = (const float*)d_in[9];
  const float* W2 = (const float*)d_in[10];
  const float* b2 = (const float*)d_in[11];
  const float* W3 = (const float*)d_in[12];
  const float* b3 = (const float*)d_in[13];

  char* ws = (char*)d_ws;
  float* U     = (float*)(ws + 0);        // 33792 f32
  float* Wc    = (float*)(ws + 135168);   // 33792 f32
  float* bias1 = (float*)(ws + 270336);   // 160 f32
  float* b1p   = (float*)(ws + 270976);   // 160 f32
  float* b2p   = (float*)(ws + 271616);   // 160 f32
  float* rb    = (float*)(ws + 272256);   // 256 f32
  // contiguous packed-weight sequence (stage chunks index off P1):
  unsigned short* P1 = (unsigned short*)(ws + 273408);  // 81920 u16 (160KB)
  unsigned short* P2 = (unsigned short*)(ws + 437248);  // 25600 u16 (50KB)
  unsigned short* P3 = (unsigned short*)(ws + 488448);  // 25600 u16 (50KB)
  unsigned short* P4 = (unsigned short*)(ws + 539648);  // 40960 u16 (80KB)
  unsigned short* csum = (unsigned short*)(ws + 621568); // [N,256] bf16, 33.5MB

  hipLaunchKernelGGL(kA, dim3(2244), dim3(256), 0, stream,
                     comp, W0, Wu, bm, bu, U, rb, csum);
  hipLaunchKernelGGL(kB, dim3(172), dim3(256), 0, stream,
                     U, Wm, W0, rb, b0, b1, b2, Wc, bias1, b1p, b2p);
  hipLaunchKernelGGL(kC, dim3(680), dim3(256), 0, stream,
                     W0, Wc, W1, W2, W3, P1, P2, P3, P4);
  hipLaunchKernelGGL(kD, dim3(512), dim3(256), 65536, stream,
                     signal, csum, P1, bias1, b1p, b2p, b3, (float*)d_out);
}